// Round 1
// baseline (511.795 us; speedup 1.0000x reference)
//
#include <hip/hip_runtime.h>

// Problem constants
#define NB     64      // batch
#define TT     2048    // time
#define INQ    8       // input size
#define CC     2       // channels
#define MM     10      // hidden m
#define TS     2047    // time steps = T-1
#define MSZ    100     // floats per matrix (10x10)
#define LCH    128     // chunk length (time steps per block)
#define NCHUNK 16      // chunks per chain (128*16 = 2048 >= 2047)
#define NCHAIN (NB*CC) // 128 chains
#define BLOCKA 320     // 64 matrices/pass * 5 threads/matrix
#define MATS_PER_PASS 64
#define K_TAYLOR 10

// Phase A: one block per (chain, chunk). Compute expm for 128 time steps,
// dyadic-tree product within the chunk, write chunk product to ws.
__global__ __launch_bounds__(BLOCKA) void phaseA(const float* __restrict__ x,
                                                 const float* __restrict__ A,
                                                 float* __restrict__ ws)
{
    __shared__ float skew_s[CC * INQ * MSZ];  // 1600 floats
    __shared__ float mat_s[LCH * MSZ];        // 12800 floats

    const int tid   = threadIdx.x;
    const int chain = blockIdx.x / NCHUNK;    // 0..127
    const int chunk = blockIdx.x % NCHUNK;    // 0..15
    const int n     = chain / CC;
    const int c     = chain % CC;

    // Load skew = A - A^T into LDS (per (c,i) 10x10)
    for (int e = tid; e < CC * INQ * MSZ; e += BLOCKA) {
        int ci = e / MSZ;
        int r  = e - ci * MSZ;
        int j  = r / MM;
        int k  = r - j * MM;
        skew_s[e] = A[ci * MSZ + j * MM + k] - A[ci * MSZ + k * MM + j];
    }
    __syncthreads();

    const int mloc = tid / 5;              // matrix within pass [0,64)
    const int j0   = 2 * (tid - 5 * mloc); // this thread's column pair {j0, j0+1}

    for (int pass = 0; pass < 2; ++pass) {
        const int slot = pass * MATS_PER_PASS + mloc;  // [0,128)
        const int t    = chunk * LCH + slot;           // global time step

        // dX increments (zero for pad slots -> G=0 -> expm=I)
        float dx[INQ];
        if (t < TS) {
            const float* xp = x + ((size_t)n * TT + t) * INQ;
            #pragma unroll
            for (int i = 0; i < INQ; ++i) dx[i] = xp[i + INQ] - xp[i];
        } else {
            #pragma unroll
            for (int i = 0; i < INQ; ++i) dx[i] = 0.0f;
        }

        // Build G columns j0, j0+1
        float g0[MM], g1[MM];
        #pragma unroll
        for (int i = 0; i < MM; ++i) { g0[i] = 0.0f; g1[i] = 0.0f; }
        #pragma unroll
        for (int ip = 0; ip < INQ; ++ip) {
            const float d = dx[ip];
            const float* sk = &skew_s[(c * INQ + ip) * MSZ];
            #pragma unroll
            for (int i = 0; i < MM; ++i) {
                g0[i] += d * sk[i * MM + j0];
                g1[i] += d * sk[i * MM + j0 + 1];
            }
        }

        // Stage G into the matrix slot (needed fully by all 5 threads of the mat)
        float* Gs = &mat_s[slot * MSZ];
        #pragma unroll
        for (int i = 0; i < MM; ++i) {
            Gs[i * MM + j0]     = g0[i];
            Gs[i * MM + j0 + 1] = g1[i];
        }
        __syncthreads();

        // expm via Taylor-Horner order K: P = I + G/1 (I + G/2 (... (I + G/K)))
        float p0[MM], p1[MM];
        #pragma unroll
        for (int i = 0; i < MM; ++i) {
            p0[i] = (i == j0)     ? 1.0f : 0.0f;
            p1[i] = (i == j0 + 1) ? 1.0f : 0.0f;
        }
        #pragma unroll
        for (int it = K_TAYLOR; it >= 1; --it) {
            float t0[MM], t1[MM];
            #pragma unroll
            for (int i = 0; i < MM; ++i) { t0[i] = 0.0f; t1[i] = 0.0f; }
            #pragma unroll
            for (int i = 0; i < MM; ++i) {
                #pragma unroll
                for (int k = 0; k < MM; ++k) {
                    const float gv = Gs[i * MM + k];
                    t0[i] += gv * p0[k];
                    t1[i] += gv * p1[k];
                }
            }
            const float inv = 1.0f / (float)it;
            #pragma unroll
            for (int i = 0; i < MM; ++i) {
                p0[i] = t0[i] * inv + ((i == j0)     ? 1.0f : 0.0f);
                p1[i] = t1[i] * inv + ((i == j0 + 1) ? 1.0f : 0.0f);
            }
        }
        __syncthreads();   // all reads of G done before overwrite

        // Write expm result over the G slot
        #pragma unroll
        for (int i = 0; i < MM; ++i) {
            Gs[i * MM + j0]     = p0[i];
            Gs[i * MM + j0 + 1] = p1[i];
        }
        __syncthreads();
    }

    // Dyadic tree product over the 128 slots, preserving time order:
    // slot[p*step] <- slot[p*step] * slot[p*step + step/2]
    for (int step = 2; step <= LCH; step <<= 1) {
        const int npair = LCH / step;
        const int nthr  = npair * 5;
        const bool active = (tid < nthr);
        float d0[MM], d1[MM];
        int aslot = 0;
        int jj0 = 0;
        if (active) {
            const int pr = tid / 5;
            jj0   = 2 * (tid - pr * 5);
            aslot = pr * step;
            const int bslot = aslot + (step >> 1);
            const float* Lm = &mat_s[aslot * MSZ];
            const float* Rm = &mat_s[bslot * MSZ];
            float r0[MM], r1[MM];
            #pragma unroll
            for (int k = 0; k < MM; ++k) {
                r0[k] = Rm[k * MM + jj0];
                r1[k] = Rm[k * MM + jj0 + 1];
            }
            #pragma unroll
            for (int i = 0; i < MM; ++i) {
                float a0 = 0.0f, a1 = 0.0f;
                #pragma unroll
                for (int k = 0; k < MM; ++k) {
                    const float lv = Lm[i * MM + k];
                    a0 += lv * r0[k];
                    a1 += lv * r1[k];
                }
                d0[i] = a0;
                d1[i] = a1;
            }
        }
        __syncthreads();   // reads complete before in-place write
        if (active) {
            float* Dm = &mat_s[aslot * MSZ];
            #pragma unroll
            for (int i = 0; i < MM; ++i) {
                Dm[i * MM + jj0]     = d0[i];
                Dm[i * MM + jj0 + 1] = d1[i];
            }
        }
        __syncthreads();
    }

    // Write chunk product
    float* wout = ws + ((size_t)chain * NCHUNK + chunk) * MSZ;
    for (int e = tid; e < MSZ; e += BLOCKA) wout[e] = mat_s[e];
}

// Phase B: one block per chain; combine the 16 chunk products (time order).
__global__ __launch_bounds__(128) void phaseB(const float* __restrict__ ws,
                                              float* __restrict__ out)
{
    __shared__ float mat_s[NCHUNK * MSZ];  // 1600 floats
    const int tid   = threadIdx.x;
    const int chain = blockIdx.x;

    for (int e = tid; e < NCHUNK * MSZ; e += 128)
        mat_s[e] = ws[(size_t)chain * NCHUNK * MSZ + e];
    __syncthreads();

    for (int step = 2; step <= NCHUNK; step <<= 1) {
        const int npair = NCHUNK / step;
        const int nthr  = npair * 5;
        const bool active = (tid < nthr);
        float d0[MM], d1[MM];
        int aslot = 0;
        int jj0 = 0;
        if (active) {
            const int pr = tid / 5;
            jj0   = 2 * (tid - pr * 5);
            aslot = pr * step;
            const int bslot = aslot + (step >> 1);
            const float* Lm = &mat_s[aslot * MSZ];
            const float* Rm = &mat_s[bslot * MSZ];
            float r0[MM], r1[MM];
            #pragma unroll
            for (int k = 0; k < MM; ++k) {
                r0[k] = Rm[k * MM + jj0];
                r1[k] = Rm[k * MM + jj0 + 1];
            }
            #pragma unroll
            for (int i = 0; i < MM; ++i) {
                float a0 = 0.0f, a1 = 0.0f;
                #pragma unroll
                for (int k = 0; k < MM; ++k) {
                    const float lv = Lm[i * MM + k];
                    a0 += lv * r0[k];
                    a1 += lv * r1[k];
                }
                d0[i] = a0;
                d1[i] = a1;
            }
        }
        __syncthreads();
        if (active) {
            float* Dm = &mat_s[aslot * MSZ];
            #pragma unroll
            for (int i = 0; i < MM; ++i) {
                Dm[i * MM + jj0]     = d0[i];
                Dm[i * MM + jj0 + 1] = d1[i];
            }
        }
        __syncthreads();
    }

    for (int e = tid; e < MSZ; e += 128)
        out[(size_t)chain * MSZ + e] = mat_s[e];
}

extern "C" void kernel_launch(void* const* d_in, const int* in_sizes, int n_in,
                              void* d_out, int out_size, void* d_ws, size_t ws_size,
                              hipStream_t stream) {
    const float* x = (const float*)d_in[0];  // (64, 2048, 8)
    const float* A = (const float*)d_in[1];  // (2, 8, 10, 10)
    float* out = (float*)d_out;              // (64, 2, 10, 10)
    float* ws  = (float*)d_ws;               // 128*16*100 floats = 819200 B

    phaseA<<<dim3(NCHAIN * NCHUNK), dim3(BLOCKA), 0, stream>>>(x, A, ws);
    phaseB<<<dim3(NCHAIN), dim3(128), 0, stream>>>(ws, out);
}

// Round 2
// 296.366 us; speedup vs baseline: 1.7269x; 1.7269x over previous
//
#include <hip/hip_runtime.h>

// Problem constants
#define NB     64      // batch
#define TT     2048    // time
#define INQ    8       // input size
#define CC     2      // channels
#define MM     10     // hidden m
#define TS     2047   // time steps = T-1
#define ROWP   12     // padded row floats (48 B, 16-aligned)
#define MATP   (MM*ROWP)   // 120 floats per padded matrix
#define SLEN   4      // sequential steps per lane-pair segment
#define SEGS   128    // segments per block
#define CHUNK  (SEGS*SLEN) // 512 steps per block
#define NCHUNK 4      // chunks per chain
#define NCHAIN (NB*CC)
#define KTAY   7      // Taylor order (||G|| <~ 0.9 -> trunc err ~4e-6)

__device__ __forceinline__ float dpp_xor1(float v) {
    // swap with partner lane (lane ^ 1) via DPP quad_perm [1,0,3,2] = 0xB1
    int i = __float_as_int(v);
    int r = __builtin_amdgcn_update_dpp(i, i, 0xB1, 0xF, 0xF, true);
    return __int_as_float(r);
}

// One block per (chain, chunk). Each lane-pair serially processes SLEN steps
// computing R <- R * expm(G_t) fully in registers (rows split across the pair,
// full G assembled per-lane via DPP), then a 7-level dyadic tree in LDS
// combines the 128 segment products into one chunk product.
__global__ __launch_bounds__(256, 2) void dev_serial(const float* __restrict__ x,
                                                     const float* __restrict__ A,
                                                     float* __restrict__ ws)
{
    __shared__ float skew_s[INQ * MATP];   // 3840 B
    __shared__ float tree_s[SEGS * MATP];  // 61440 B   (total 65280 <= 64 KiB)

    const int tid   = threadIdx.x;
    const int chain = blockIdx.x >> 2;   // / NCHUNK
    const int chunk = blockIdx.x & 3;
    const int n     = chain >> 1;        // / CC
    const int c     = chain & 1;

    // Stage skew = A - A^T for our channel, padded rows (pad = 0)
    for (int e = tid; e < INQ * MATP; e += 256) {
        const int ip  = e / MATP;
        const int rem = e - ip * MATP;
        const int i   = rem / ROWP;
        const int j   = rem - i * ROWP;
        float v = 0.0f;
        if (j < MM) {
            const float* Ab = A + (size_t)(c * INQ + ip) * (MM * MM);
            v = Ab[i * MM + j] - Ab[j * MM + i];
        }
        skew_s[e] = v;
    }
    __syncthreads();

    const int seg = tid >> 1;
    const int p   = tid & 1;     // parity: this lane owns global rows r0..r0+4
    const int r0  = p * 5;

    // Running product rows (identity init)
    float R[5][MM];
    #pragma unroll
    for (int r = 0; r < 5; ++r)
        #pragma unroll
        for (int j = 0; j < MM; ++j)
            R[r][j] = (j == r0 + r) ? 1.0f : 0.0f;

    const float* xb = x + (size_t)n * TT * INQ;
    int t = chunk * CHUNK + seg * SLEN;

    float xc[INQ];
    {
        const float4* xp = reinterpret_cast<const float4*>(xb + (size_t)t * INQ);
        float4 a = xp[0], b = xp[1];
        xc[0] = a.x; xc[1] = a.y; xc[2] = a.z; xc[3] = a.w;
        xc[4] = b.x; xc[5] = b.y; xc[6] = b.z; xc[7] = b.w;
    }

    #pragma unroll 1
    for (int s = 0; s < SLEN; ++s) {
        // next x (clamped: t+1 == 2048 -> reuse 2047 -> dx = 0 -> E = I)
        int tn = t + 1; if (tn > TS) tn = TS;
        float dx[INQ];
        {
            const float4* xp = reinterpret_cast<const float4*>(xb + (size_t)tn * INQ);
            float4 a = xp[0], b = xp[1];
            dx[0] = a.x - xc[0]; dx[1] = a.y - xc[1]; dx[2] = a.z - xc[2]; dx[3] = a.w - xc[3];
            dx[4] = b.x - xc[4]; dx[5] = b.y - xc[5]; dx[6] = b.z - xc[6]; dx[7] = b.w - xc[7];
            xc[0] = a.x; xc[1] = a.y; xc[2] = a.z; xc[3] = a.w;
            xc[4] = b.x; xc[5] = b.y; xc[6] = b.z; xc[7] = b.w;
        }
        t = t + 1;

        // Build my half of G (rows r0..r0+4) from LDS skew (float4 reads, broadcast)
        float gm[5][MM];
        #pragma unroll
        for (int r = 0; r < 5; ++r)
            #pragma unroll
            for (int j = 0; j < MM; ++j)
                gm[r][j] = 0.0f;
        #pragma unroll
        for (int ip = 0; ip < INQ; ++ip) {
            const float d = dx[ip];
            #pragma unroll
            for (int r = 0; r < 5; ++r) {
                const float4* srow = reinterpret_cast<const float4*>(
                    &skew_s[(ip * MM + r0 + r) * ROWP]);
                float4 s0 = srow[0], s1 = srow[1], s2 = srow[2];
                gm[r][0] += d * s0.x; gm[r][1] += d * s0.y;
                gm[r][2] += d * s0.z; gm[r][3] += d * s0.w;
                gm[r][4] += d * s1.x; gm[r][5] += d * s1.y;
                gm[r][6] += d * s1.z; gm[r][7] += d * s1.w;
                gm[r][8] += d * s2.x; gm[r][9] += d * s2.y;
            }
        }

        // Assemble full G in registers: partner half via DPP, select by parity
        float G[MM][MM];
        #pragma unroll
        for (int r = 0; r < 5; ++r) {
            #pragma unroll
            for (int j = 0; j < MM; ++j) {
                const float loc = gm[r][j];
                const float rem = dpp_xor1(loc);
                G[r][j]     = p ? rem : loc;   // global rows 0..4
                G[5 + r][j] = p ? loc : rem;   // global rows 5..9
            }
        }

        // R <- R * expm(G):  Acc_0 = R;  Acc_j = Acc_{j-1} * (G / j);  R += Acc_j
        float Acc[5][MM];
        #pragma unroll
        for (int r = 0; r < 5; ++r)
            #pragma unroll
            for (int j = 0; j < MM; ++j)
                Acc[r][j] = R[r][j];

        #pragma unroll 1
        for (int jt = 1; jt <= KTAY; ++jt) {
            const float inv = 1.0f / (float)jt;
            #pragma unroll
            for (int r = 0; r < 5; ++r) {
                float tr[MM];
                #pragma unroll
                for (int j = 0; j < MM; ++j) tr[j] = 0.0f;
                #pragma unroll
                for (int k = 0; k < MM; ++k) {
                    const float av = Acc[r][k];
                    #pragma unroll
                    for (int j = 0; j < MM; ++j)
                        tr[j] += av * G[k][j];
                }
                #pragma unroll
                for (int j = 0; j < MM; ++j) {
                    const float nv = tr[j] * inv;
                    Acc[r][j] = nv;
                    R[r][j]  += nv;
                }
            }
        }
    }

    // Store segment product to tree (padded rows, pad = 0)
    {
        float* dst = &tree_s[seg * MATP + r0 * ROWP];
        #pragma unroll
        for (int r = 0; r < 5; ++r) {
            float4* drow = reinterpret_cast<float4*>(dst + r * ROWP);
            drow[0] = make_float4(R[r][0], R[r][1], R[r][2], R[r][3]);
            drow[1] = make_float4(R[r][4], R[r][5], R[r][6], R[r][7]);
            drow[2] = make_float4(R[r][8], R[r][9], 0.0f, 0.0f);
        }
    }
    __syncthreads();

    // Dyadic tree: 7 levels, product q: slot[q*span] <- slot[q*span] * slot[q*span+span/2]
    #pragma unroll 1
    for (int span = 2; span <= SEGS; span <<= 1) {
        const int np = SEGS / span;        // products this level
        if (tid < 2 * np) {
            const int q  = tid >> 1;
            const int pq = tid & 1;
            const int ls = q * span;
            const int rs = ls + (span >> 1);

            // load my half-rows of L
            float lrow[5][MM];
            #pragma unroll
            for (int r = 0; r < 5; ++r) {
                const float4* lr = reinterpret_cast<const float4*>(
                    &tree_s[ls * MATP + (pq * 5 + r) * ROWP]);
                float4 a = lr[0], b = lr[1], c4 = lr[2];
                lrow[r][0] = a.x;  lrow[r][1] = a.y;  lrow[r][2] = a.z;  lrow[r][3] = a.w;
                lrow[r][4] = b.x;  lrow[r][5] = b.y;  lrow[r][6] = b.z;  lrow[r][7] = b.w;
                lrow[r][8] = c4.x; lrow[r][9] = c4.y;
            }

            float d[5][MM];
            #pragma unroll
            for (int r = 0; r < 5; ++r)
                #pragma unroll
                for (int j = 0; j < MM; ++j)
                    d[r][j] = 0.0f;

            #pragma unroll
            for (int k = 0; k < MM; ++k) {
                const float4* rr = reinterpret_cast<const float4*>(
                    &tree_s[rs * MATP + k * ROWP]);
                float4 a = rr[0], b = rr[1], c4 = rr[2];
                float rrow[MM];
                rrow[0] = a.x;  rrow[1] = a.y;  rrow[2] = a.z;  rrow[3] = a.w;
                rrow[4] = b.x;  rrow[5] = b.y;  rrow[6] = b.z;  rrow[7] = b.w;
                rrow[8] = c4.x; rrow[9] = c4.y;
                #pragma unroll
                for (int r = 0; r < 5; ++r) {
                    const float lv = lrow[r][k];
                    #pragma unroll
                    for (int j = 0; j < MM; ++j)
                        d[r][j] += lv * rrow[j];
                }
            }

            // write back into L slot (pair is wave-lockstep; slots disjoint per wave)
            float* dst = &tree_s[ls * MATP + pq * 5 * ROWP];
            #pragma unroll
            for (int r = 0; r < 5; ++r) {
                float4* drow = reinterpret_cast<float4*>(dst + r * ROWP);
                drow[0] = make_float4(d[r][0], d[r][1], d[r][2], d[r][3]);
                drow[1] = make_float4(d[r][4], d[r][5], d[r][6], d[r][7]);
                drow[2] = make_float4(d[r][8], d[r][9], 0.0f, 0.0f);
            }
        }
        __syncthreads();
    }

    // slot 0 = chunk product -> ws (unpadded 100 floats)
    if (tid < 100) {
        const int i = tid / 10;
        const int j = tid - i * 10;
        ws[((size_t)chain * NCHUNK + chunk) * 100 + tid] = tree_s[i * ROWP + j];
    }
}

// Combine NCHUNK chunk products per chain. One thread per (chain, row).
__global__ __launch_bounds__(256) void dev_combine(const float* __restrict__ ws,
                                                   float* __restrict__ out)
{
    const int id = blockIdx.x * 256 + threadIdx.x;
    if (id >= NCHAIN * MM) return;
    const int chain = id / MM;
    const int r     = id - chain * MM;

    const float* base = ws + (size_t)chain * NCHUNK * 100;
    float R[MM];
    #pragma unroll
    for (int j = 0; j < MM; ++j) R[j] = base[r * MM + j];

    #pragma unroll
    for (int ck = 1; ck < NCHUNK; ++ck) {
        const float* Mb = base + ck * 100;
        float Rn[MM];
        #pragma unroll
        for (int j = 0; j < MM; ++j) Rn[j] = 0.0f;
        #pragma unroll
        for (int k = 0; k < MM; ++k) {
            const float rv = R[k];
            #pragma unroll
            for (int j = 0; j < MM; ++j)
                Rn[j] += rv * Mb[k * MM + j];
        }
        #pragma unroll
        for (int j = 0; j < MM; ++j) R[j] = Rn[j];
    }

    #pragma unroll
    for (int j = 0; j < MM; ++j)
        out[(size_t)chain * 100 + r * MM + j] = R[j];
}

extern "C" void kernel_launch(void* const* d_in, const int* in_sizes, int n_in,
                              void* d_out, int out_size, void* d_ws, size_t ws_size,
                              hipStream_t stream) {
    (void)in_sizes; (void)n_in; (void)out_size; (void)ws_size;
    const float* x = (const float*)d_in[0];  // (64, 2048, 8)
    const float* A = (const float*)d_in[1];  // (2, 8, 10, 10)
    float* out = (float*)d_out;              // (64, 2, 10, 10)
    float* ws  = (float*)d_ws;               // 128*4*100 floats = 204800 B

    dev_serial<<<dim3(NCHAIN * NCHUNK), dim3(256), 0, stream>>>(x, A, ws);
    dev_combine<<<dim3((NCHAIN * MM + 255) / 256), dim3(256), 0, stream>>>(ws, out);
}